// Round 10
// baseline (20.268 us; speedup 1.0000x reference)
//
#include <hip/hip_runtime.h>
#include <math.h>

// Problem constants: B=8, P=512, G=128, C=68
#define B_ 8
#define P_ 512
#define G_ 128
#define C_ 68
#define BG (B_ * G_)   // 1024
#define BP (B_ * P_)   // 4096
#define NBLK 256       // blocks; each owns 4 gts (4 waves per gt)
#define EPS_ 1.0f      // AABB slack: excluded pairs have >1px gap -> exact 0 in ref

// Single kernel, single graph node, NO memset node (R4/R5 showed in-graph
// hipMemsetAsync costs ~20us). 256 blocks x 1024 thr (16 waves).
// Wave w: gt-local g = w>>2, slice s = w&3; gt bg = blk*4+g (all same batch).
//  - slice wave scans preds [s*128,(s+1)*128) in 2 ballot rounds into its
//    private segment (ascending p; 4 segments concatenate to the SAME
//    ascending-p survivor list as validated R9)
//  - barrier; s==0 waves clip their gt (R8-validated dechained CLIP_EDGE,
//    bit-identical FP) + argmax + 68-wide log-softmax CE -> s_ce[g]/s_co[g]
//  - barrier; t==0: fixed-order 4-sum, pack, volatile slot store,
//    __threadfence release, counter ticket (R7-proven pattern; winner
//    (tic&255)==255 works from ANY initial counter value, 2^32%256==0)
//  - barrier; winner block: __threadfence acquire, fixed-tree 256-slot
//    reduce (bitwise deterministic regardless of winner), write out[3].
// No wave returns early: all branches block-uniform around barriers.
#define CLIP_EDGE(E, INX, INY, OUTX, OUTY)                                   \
    {                                                                        \
        const float eax = ccx[E], eay = ccy[E];                              \
        const float ex = ccx[(E + 1) & 3] - eax;                             \
        const float ey = ccy[(E + 1) & 3] - eay;                             \
        float vx[8], vy[8], dp[8];                                           \
        bool  vin[8];                                                        \
        _Pragma("unroll")                                                    \
        for (int i = 0; i < 8; ++i) {                                        \
            vx[i] = INX[i * 64 + lane];                                      \
            vy[i] = INY[i * 64 + lane];                                      \
        }                                                                    \
        _Pragma("unroll")                                                    \
        for (int i = 0; i < 8; ++i) {                                        \
            dp[i]  = ex * (vy[i] - eay) - ey * (vx[i] - eax);                \
            vin[i] = (dp[i] >= 0.0f);                                        \
        }                                                                    \
        int m = 0;                                                           \
        _Pragma("unroll")                                                    \
        for (int i = 0; i < 8; ++i) {                                        \
            if (i < n) {                                                     \
                const bool wrap = (i + 1 == n);                              \
                const int  jn   = (i + 1) & 7;                               \
                const float qx = wrap ? vx[0] : vx[jn];                      \
                const float qy = wrap ? vy[0] : vy[jn];                      \
                const float dq = wrap ? dp[0] : dp[jn];                      \
                const bool  inq = (dq >= 0.0f);                              \
                if (vin[i]) {                                                \
                    if (m < 8) { OUTX[m * 64 + lane] = vx[i];                \
                                 OUTY[m * 64 + lane] = vy[i]; }              \
                    ++m;                                                     \
                }                                                            \
                if (vin[i] != inq) {                                         \
                    const float den = dp[i] - dq;                            \
                    const float tt = (den == 0.0f) ? 0.0f : dp[i] / den;     \
                    if (m < 8) {                                             \
                        OUTX[m * 64 + lane] = vx[i] + tt * (qx - vx[i]);     \
                        OUTY[m * 64 + lane] = vy[i] + tt * (qy - vy[i]);     \
                    }                                                        \
                    ++m;                                                     \
                }                                                            \
            }                                                                \
        }                                                                    \
        n = (m > 8) ? 8 : m;                                                 \
    }

__global__ __launch_bounds__(1024) void fused_kernel(
    const float* __restrict__ bboxes,   // [BP,9]
    const float* __restrict__ scores,   // [BP,C]
    const float* __restrict__ polys,    // [BG,4,2]
    const int*   __restrict__ labels,   // [BG]
    unsigned long long* __restrict__ slots,  // [NBLK] ws (no init needed)
    unsigned int* __restrict__ counter,      // [1] ws (any value OK)
    float* __restrict__ out)            // [3]
{
#pragma clang fp contract(off)
    const int blk  = blockIdx.x;        // 0..255
    const int t    = threadIdx.x;       // 0..1023
    const int w    = t >> 6;            // wave 0..15
    const int lane = t & 63;
    const int g    = w >> 2;            // gt-local 0..3
    const int s    = w & 3;             // slice 0..3
    const int bg   = (blk << 2) | g;    // 0..1023
    const int b    = bg >> 7;           // batch (uniform per block)

    __shared__ int   s_seg[16 * 128];   // [g*4+s][128]
    __shared__ int   s_cnt[16];
    __shared__ float s_px[4 * 512], s_py[4 * 512];  // per-gt clip buffers
    __shared__ float s_qx[4 * 512], s_qy[4 * 512];
    __shared__ float s_ce[4];
    __shared__ int   s_co[4];
    __shared__ int   s_last;
    __shared__ float ra[4];
    __shared__ int   rc[4];

    // ---- gt prep (bit-identical to validated rounds) ----
    const float* cp = polys + (size_t)bg * 8;
    const float x0 = cp[0], y0 = cp[1], x1 = cp[2], y1 = cp[3];
    const float x2 = cp[4], y2 = cp[5], x3 = cp[6], y3 = cp[7];
    const float sa = (x0 * y1 - x1 * y0) + (x1 * y2 - x2 * y1)
                   + (x2 * y3 - x3 * y2) + (x3 * y0 - x0 * y3);
    const bool rev = (sa < 0.0f);
    float ccx[4], ccy[4];
    ccx[0] = rev ? x3 : x0; ccy[0] = rev ? y3 : y0;
    ccx[1] = rev ? x2 : x1; ccy[1] = rev ? y2 : y1;
    ccx[2] = rev ? x1 : x2; ccy[2] = rev ? y1 : y2;
    ccx[3] = rev ? x0 : x3; ccy[3] = rev ? y0 : y3;
    const bool gt_deg =
        (x0 == x1 && y0 == y1) || (x0 == x2 && y0 == y2) ||
        (x0 == x3 && y0 == y3) || (x1 == x2 && y1 == y2) ||
        (x1 == x3 && y1 == y3) || (x2 == x3 && y2 == y3);
    const float glox = fminf(fminf(x0, x1), fminf(x2, x3)) - EPS_;
    const float gloy = fminf(fminf(y0, y1), fminf(y2, y3)) - EPS_;
    const float ghix = fmaxf(fmaxf(x0, x1), fmaxf(x2, x3)) + EPS_;
    const float ghiy = fmaxf(fmaxf(y0, y1), fmaxf(y2, y3)) + EPS_;

    // ---- scan: slice wave covers preds [s*128, s*128+128), 2 rounds ----
    const float* bbb = bboxes + (size_t)b * P_ * 9;
    {
        int base = 0;
        #pragma unroll
        for (int r = 0; r < 2; ++r) {
            const int p = (s << 7) + (r << 6) + lane;
            const float* bb = bbb + (size_t)p * 9;
            const float a0 = bb[0], a1 = bb[1], a2 = bb[2], a3 = bb[3];
            const float a4 = bb[4], a5 = bb[5], a6 = bb[6], a7 = bb[7];
            const bool deg =
                (a0 == a2 && a1 == a3) || (a0 == a4 && a1 == a5) ||
                (a0 == a6 && a1 == a7) || (a2 == a4 && a3 == a5) ||
                (a2 == a6 && a3 == a7) || (a4 == a6 && a5 == a7);
            const float lox = fminf(fminf(a0, a2), fminf(a4, a6));
            const float loy = fminf(fminf(a1, a3), fminf(a5, a7));
            const float hix = fmaxf(fmaxf(a0, a2), fmaxf(a4, a6));
            const float hiy = fmaxf(fmaxf(a1, a3), fmaxf(a5, a7));
            const bool ov = !deg &&
                (lox <= ghix) && (glox <= hix) &&
                (loy <= ghiy) && (gloy <= hiy);
            const unsigned long long mask = __ballot(ov);
            if (ov) {
                const int pre = __builtin_amdgcn_mbcnt_hi(
                    (unsigned int)(mask >> 32),
                    __builtin_amdgcn_mbcnt_lo((unsigned int)mask, 0u));
                s_seg[(((g << 2) | s) << 7) + base + pre] = p;
            }
            base += __popcll(mask);
        }
        if (lane == 0) s_cnt[(g << 2) | s] = base;
    }
    __syncthreads();

    if (s == 0) {   // clip wave for gt g (block-uniform per wave; no returns)
        const int c0 = s_cnt[(g << 2) + 0], c1 = s_cnt[(g << 2) + 1];
        const int c2 = s_cnt[(g << 2) + 2], c3 = s_cnt[(g << 2) + 3];
        const int o1 = c0, o2 = c0 + c1, o3 = c0 + c1 + c2;
        const int ns = o3 + c3;

        float* wpx = s_px + (g << 9);
        float* wpy = s_py + (g << 9);
        float* wqx = s_qx + (g << 9);
        float* wqy = s_qy + (g << 9);

        float bestA = 0.0f;
        int   bestI = 0x7fffffff;

        for (int k0 = 0; k0 < ns; k0 += 64) {
            const int k = k0 + lane;
            if (k < ns) {
                const int ws2 = (k >= o1 ? 1 : 0) + (k >= o2 ? 1 : 0) + (k >= o3 ? 1 : 0);
                const int off = (k >= o3) ? o3 : ((k >= o2) ? o2 : ((k >= o1) ? o1 : 0));
                const int p   = s_seg[(((g << 2) | ws2) << 7) + (k - off)];
                const float* bb = bbb + (size_t)p * 9;
                int n = 4;

                // edge 0: subject quad in registers, n == 4 static
                {
                    float vx[4], vy[4], dp[4];
                    bool  vin[4];
                    vx[0] = bb[0]; vy[0] = bb[1];
                    vx[1] = bb[2]; vy[1] = bb[3];
                    vx[2] = bb[4]; vy[2] = bb[5];
                    vx[3] = bb[6]; vy[3] = bb[7];
                    const float eax = ccx[0], eay = ccy[0];
                    const float ex = ccx[1] - eax;
                    const float ey = ccy[1] - eay;
                    #pragma unroll
                    for (int i = 0; i < 4; ++i) {
                        dp[i]  = ex * (vy[i] - eay) - ey * (vx[i] - eax);
                        vin[i] = (dp[i] >= 0.0f);
                    }
                    int m = 0;
                    #pragma unroll
                    for (int i = 0; i < 4; ++i) {
                        const int j = (i + 1) & 3;
                        if (vin[i]) {
                            if (m < 8) { wqx[m * 64 + lane] = vx[i];
                                         wqy[m * 64 + lane] = vy[i]; }
                            ++m;
                        }
                        if (vin[i] != vin[j]) {
                            const float den = dp[i] - dp[j];
                            const float tt = (den == 0.0f) ? 0.0f : dp[i] / den;
                            if (m < 8) {
                                wqx[m * 64 + lane] = vx[i] + tt * (vx[j] - vx[i]);
                                wqy[m * 64 + lane] = vy[i] + tt * (vy[j] - vy[i]);
                            }
                            ++m;
                        }
                    }
                    n = (m > 8) ? 8 : m;
                }

                CLIP_EDGE(1, wqx, wqy, wpx, wpy)
                CLIP_EDGE(2, wpx, wpy, wqx, wqy)
                CLIP_EDGE(3, wqx, wqy, wpx, wpy)

                float ssum = 0.0f;
                {
                    float vx[8], vy[8];
                    #pragma unroll
                    for (int i = 0; i < 8; ++i) {
                        vx[i] = wpx[i * 64 + lane];
                        vy[i] = wpy[i * 64 + lane];
                    }
                    #pragma unroll
                    for (int i = 0; i < 8; ++i) {
                        if (i < n) {
                            const bool wrap = (i + 1 == n);
                            const int  jn   = (i + 1) & 7;
                            const float qx = wrap ? vx[0] : vx[jn];
                            const float qy = wrap ? vy[0] : vy[jn];
                            ssum += vx[i] * qy - qx * vy[i];
                        }
                    }
                }
                const float area = fabsf(0.5f * ssum);
                if (area > bestA || (area == bestA && p < bestI)) {
                    bestA = area; bestI = p;
                }
            }
        }

        #pragma unroll
        for (int off = 32; off; off >>= 1) {
            const float oa = __shfl_xor(bestA, off);
            const int   oi = __shfl_xor(bestI, off);
            if (oa > bestA || (oa == bestA && oi < bestI)) { bestA = oa; bestI = oi; }
        }

        const bool matched = (!gt_deg) && (bestA != 0.0f);
        const int label = labels[bg];

        float ce_val; int co_val;
        if (matched) {
            const float* sc = scores + (size_t)(b * P_ + bestI) * C_;
            const float v0 = sc[lane];
            const bool  h2 = (lane + 64) < C_;
            const float v1 = h2 ? sc[lane + 64] : -3e38f;
            float bv; int bi;
            if (v1 > v0) { bv = v1; bi = lane + 64; } else { bv = v0; bi = lane; }
            float mx = fmaxf(v0, v1);
            #pragma unroll
            for (int off = 32; off; off >>= 1) mx = fmaxf(mx, __shfl_xor(mx, off));
            #pragma unroll
            for (int off = 32; off; off >>= 1) {
                const float ov2 = __shfl_xor(bv, off);
                const int   oi2 = __shfl_xor(bi, off);
                if (ov2 > bv || (ov2 == bv && oi2 < bi)) { bv = ov2; bi = oi2; }
            }
            float e = expf(v0 - mx) + (h2 ? expf(v1 - mx) : 0.0f);
            #pragma unroll
            for (int off = 32; off; off >>= 1) e += __shfl_xor(e, off);
            ce_val = mx + logf(e) - sc[label];
            co_val = (bi == label) ? 1 : 0;
        } else {
            ce_val = logf((float)C_);
            co_val = 0;
        }
        if (lane == 0) { s_ce[g] = ce_val; s_co[g] = co_val; }
    }
    __syncthreads();

    if (t == 0) {
        // fixed-order block partial (bitwise deterministic)
        const float a = ((s_ce[0] + s_ce[1]) + s_ce[2]) + s_ce[3];
        const int   c = s_co[0] + s_co[1] + s_co[2] + s_co[3];
        const unsigned long long pack =
            ((unsigned long long)__float_as_uint(a) << 32) | (unsigned int)c;
        *(volatile unsigned long long*)&slots[blk] = pack;
        __threadfence();                         // release (R7-proven)
        const unsigned int tic = atomicAdd(counter, 1u);
        s_last = ((tic & (unsigned)(NBLK - 1)) == (unsigned)(NBLK - 1)) ? 1 : 0;
    }
    __syncthreads();

    if (s_last) {                                // block-uniform branch
        __threadfence();                         // acquire
        float fa = 0.0f; int fc = 0;
        if (t < NBLK) {
            const unsigned long long v =
                *(volatile const unsigned long long*)&slots[t];
            fa = __uint_as_float((unsigned int)(v >> 32));
            fc = (int)(unsigned int)(v & 0xffffffffULL);
            #pragma unroll
            for (int off = 32; off; off >>= 1) {
                fa += __shfl_xor(fa, off);
                fc += __shfl_xor(fc, off);
            }
            if (lane == 0) { ra[w] = fa; rc[w] = fc; }
        }
        __syncthreads();                         // block-uniform: OK
        if (t == 0) {
            const float stot = (ra[0] + ra[1]) + (ra[2] + ra[3]);
            const int   ctot = rc[0] + rc[1] + rc[2] + rc[3];
            out[0] = stot * (1.0f / (float)BG);  // mean ce
            out[1] = (float)BG;                  // total_number
            out[2] = (float)ctot;                // rec_correct
        }
    }
}

extern "C" void kernel_launch(void* const* d_in, const int* in_sizes, int n_in,
                              void* d_out, int out_size, void* d_ws, size_t ws_size,
                              hipStream_t stream) {
    const float* bboxes = (const float*)d_in[0];   // [B,P,9]
    const float* scores = (const float*)d_in[1];   // [B,P,C]
    const float* polys  = (const float*)d_in[2];   // [B,G,4,2]
    const int*   labels = (const int*)d_in[3];     // [B,G]
    float* out = (float*)d_out;

    unsigned long long* slots   = (unsigned long long*)d_ws;            // [NBLK]
    unsigned int*       counter = (unsigned int*)((char*)d_ws + 4096);

    fused_kernel<<<NBLK, 1024, 0, stream>>>(bboxes, scores, polys, labels,
                                            slots, counter, out);
}

// Round 11
// 14.421 us; speedup vs baseline: 1.4055x; 1.4055x over previous
//
#include <hip/hip_runtime.h>
#include <math.h>

// Problem constants: B=8, P=512, G=128, C=68
#define B_ 8
#define P_ 512
#define G_ 128
#define C_ 68
#define BG (B_ * G_)   // 1024
#define BP (B_ * P_)   // 4096
#define EPS_ 1.0f      // AABB slack: excluded pairs have >1px gap -> exact 0 in ref

// R9 structure (best validated: 15.0us): one 256-thread block (4 waves) per
// (b,g); 4 slice-waves scan 128 preds each (2 ballot rounds) into private
// LDS segments (concatenation == ascending-p survivor list, bit-identical
// to the validated 1-wave scan); wave 0 clips with the R8-validated
// dechained CLIP_EDGE + packed-u64 single-pass softmax argmax.
#define CLIP_EDGE(E, INX, INY, OUTX, OUTY)                                   \
    {                                                                        \
        const float eax = ccx[E], eay = ccy[E];                              \
        const float ex = ccx[(E + 1) & 3] - eax;                             \
        const float ey = ccy[(E + 1) & 3] - eay;                             \
        float vx[8], vy[8], dp[8];                                           \
        bool  vin[8];                                                        \
        _Pragma("unroll")                                                    \
        for (int i = 0; i < 8; ++i) {                                        \
            vx[i] = INX[i * 64 + lane];                                      \
            vy[i] = INY[i * 64 + lane];                                      \
        }                                                                    \
        _Pragma("unroll")                                                    \
        for (int i = 0; i < 8; ++i) {                                        \
            dp[i]  = ex * (vy[i] - eay) - ey * (vx[i] - eax);                \
            vin[i] = (dp[i] >= 0.0f);                                        \
        }                                                                    \
        int m = 0;                                                           \
        _Pragma("unroll")                                                    \
        for (int i = 0; i < 8; ++i) {                                        \
            if (i < n) {                                                     \
                const bool wrap = (i + 1 == n);                              \
                const int  jn   = (i + 1) & 7;                               \
                const float qx = wrap ? vx[0] : vx[jn];                      \
                const float qy = wrap ? vy[0] : vy[jn];                      \
                const float dq = wrap ? dp[0] : dp[jn];                      \
                const bool  inq = (dq >= 0.0f);                              \
                if (vin[i]) {                                                \
                    if (m < 8) { OUTX[m * 64 + lane] = vx[i];                \
                                 OUTY[m * 64 + lane] = vy[i]; }              \
                    ++m;                                                     \
                }                                                            \
                if (vin[i] != inq) {                                         \
                    const float den = dp[i] - dq;                            \
                    const float tt = (den == 0.0f) ? 0.0f : dp[i] / den;     \
                    if (m < 8) {                                             \
                        OUTX[m * 64 + lane] = vx[i] + tt * (qx - vx[i]);     \
                        OUTY[m * 64 + lane] = vy[i] + tt * (qy - vy[i]);     \
                    }                                                        \
                    ++m;                                                     \
                }                                                            \
            }                                                                \
        }                                                                    \
        n = (m > 8) ? 8 : m;                                                 \
    }

__device__ __forceinline__ unsigned map_orderable(float f) {
    const unsigned u = __float_as_uint(f);
    return (u & 0x80000000u) ? ~u : (u | 0x80000000u);
}

__global__ __launch_bounds__(256) void match_kernel(
    const float* __restrict__ bboxes,   // [BP,9]
    const float* __restrict__ scores,   // [BP,C]
    const float* __restrict__ polys,    // [BG,4,2]
    const int*   __restrict__ labels,   // [BG]
    float* __restrict__ ce_out,         // [BG]
    int*   __restrict__ corr_out)       // [BG]
{
#pragma clang fp contract(off)
    const int bg   = blockIdx.x;
    const int b    = bg >> 7;           // / G_
    const int t    = threadIdx.x;       // 0..255
    const int w    = t >> 6;            // wave 0..3
    const int lane = t & 63;

    __shared__ int   s_seg[4 * 128];    // per-wave survivor segments
    __shared__ int   s_cnt[4];
    __shared__ float s_px[8 * 64], s_py[8 * 64];
    __shared__ float s_qx[8 * 64], s_qy[8 * 64];

    // ---- gt prep (bit-identical to validated rounds; all threads) ----
    const float* cp = polys + (size_t)bg * 8;
    const float x0 = cp[0], y0 = cp[1], x1 = cp[2], y1 = cp[3];
    const float x2 = cp[4], y2 = cp[5], x3 = cp[6], y3 = cp[7];
    const float sa = (x0 * y1 - x1 * y0) + (x1 * y2 - x2 * y1)
                   + (x2 * y3 - x3 * y2) + (x3 * y0 - x0 * y3);
    const bool rev = (sa < 0.0f);
    float ccx[4], ccy[4];
    ccx[0] = rev ? x3 : x0; ccy[0] = rev ? y3 : y0;
    ccx[1] = rev ? x2 : x1; ccy[1] = rev ? y2 : y1;
    ccx[2] = rev ? x1 : x2; ccy[2] = rev ? y1 : y2;
    ccx[3] = rev ? x0 : x3; ccy[3] = rev ? y0 : y3;
    const bool gt_deg =
        (x0 == x1 && y0 == y1) || (x0 == x2 && y0 == y2) ||
        (x0 == x3 && y0 == y3) || (x1 == x2 && y1 == y2) ||
        (x1 == x3 && y1 == y3) || (x2 == x3 && y2 == y3);
    const float glox = fminf(fminf(x0, x1), fminf(x2, x3)) - EPS_;
    const float gloy = fminf(fminf(y0, y1), fminf(y2, y3)) - EPS_;
    const float ghix = fmaxf(fmaxf(x0, x1), fmaxf(x2, x3)) + EPS_;
    const float ghiy = fmaxf(fmaxf(y0, y1), fmaxf(y2, y3)) + EPS_;

    // ---- scan: wave w covers preds [w*128, w*128+128), 2 ballot rounds ----
    const float* bbb = bboxes + (size_t)b * P_ * 9;
    {
        int base = 0;
        #pragma unroll
        for (int r = 0; r < 2; ++r) {
            const int p = (w << 7) + (r << 6) + lane;
            const float* bb = bbb + (size_t)p * 9;
            const float a0 = bb[0], a1 = bb[1], a2 = bb[2], a3 = bb[3];
            const float a4 = bb[4], a5 = bb[5], a6 = bb[6], a7 = bb[7];
            const bool deg =
                (a0 == a2 && a1 == a3) || (a0 == a4 && a1 == a5) ||
                (a0 == a6 && a1 == a7) || (a2 == a4 && a3 == a5) ||
                (a2 == a6 && a3 == a7) || (a4 == a6 && a5 == a7);
            const float lox = fminf(fminf(a0, a2), fminf(a4, a6));
            const float loy = fminf(fminf(a1, a3), fminf(a5, a7));
            const float hix = fmaxf(fmaxf(a0, a2), fmaxf(a4, a6));
            const float hiy = fmaxf(fmaxf(a1, a3), fmaxf(a5, a7));
            const bool ov = !deg &&
                (lox <= ghix) && (glox <= hix) &&
                (loy <= ghiy) && (gloy <= hiy);
            const unsigned long long mask = __ballot(ov);
            if (ov) {
                const int pre = __builtin_amdgcn_mbcnt_hi(
                    (unsigned int)(mask >> 32),
                    __builtin_amdgcn_mbcnt_lo((unsigned int)mask, 0u));
                s_seg[(w << 7) + base + pre] = p;
            }
            base += __popcll(mask);
        }
        if (lane == 0) s_cnt[w] = base;
    }
    __syncthreads();

    if (w != 0) return;   // wave 0 only from here; no further barriers

    const int c0 = s_cnt[0], c1 = s_cnt[1], c2 = s_cnt[2], c3 = s_cnt[3];
    const int o1 = c0, o2 = c0 + c1, o3 = c0 + c1 + c2;
    const int ns = o3 + c3;

    // ---- clip survivors (R8-validated dechained SH, bit-identical) ----
    float bestA = 0.0f;
    int   bestI = 0x7fffffff;

    for (int k0 = 0; k0 < ns; k0 += 64) {
        const int k = k0 + lane;
        if (k < ns) {
            const int ws  = (k >= o1 ? 1 : 0) + (k >= o2 ? 1 : 0) + (k >= o3 ? 1 : 0);
            const int off = (k >= o3) ? o3 : ((k >= o2) ? o2 : ((k >= o1) ? o1 : 0));
            const int p   = s_seg[(ws << 7) + (k - off)];
            const float* bb = bbb + (size_t)p * 9;
            int n = 4;

            // edge 0: subject quad in registers, n == 4 static
            {
                float vx[4], vy[4], dp[4];
                bool  vin[4];
                vx[0] = bb[0]; vy[0] = bb[1];
                vx[1] = bb[2]; vy[1] = bb[3];
                vx[2] = bb[4]; vy[2] = bb[5];
                vx[3] = bb[6]; vy[3] = bb[7];
                const float eax = ccx[0], eay = ccy[0];
                const float ex = ccx[1] - eax;
                const float ey = ccy[1] - eay;
                #pragma unroll
                for (int i = 0; i < 4; ++i) {
                    dp[i]  = ex * (vy[i] - eay) - ey * (vx[i] - eax);
                    vin[i] = (dp[i] >= 0.0f);
                }
                int m = 0;
                #pragma unroll
                for (int i = 0; i < 4; ++i) {
                    const int j = (i + 1) & 3;
                    if (vin[i]) {
                        if (m < 8) { s_qx[m * 64 + lane] = vx[i];
                                     s_qy[m * 64 + lane] = vy[i]; }
                        ++m;
                    }
                    if (vin[i] != vin[j]) {
                        const float den = dp[i] - dp[j];
                        const float tt = (den == 0.0f) ? 0.0f : dp[i] / den;
                        if (m < 8) {
                            s_qx[m * 64 + lane] = vx[i] + tt * (vx[j] - vx[i]);
                            s_qy[m * 64 + lane] = vy[i] + tt * (vy[j] - vy[i]);
                        }
                        ++m;
                    }
                }
                n = (m > 8) ? 8 : m;
            }

            CLIP_EDGE(1, s_qx, s_qy, s_px, s_py)
            CLIP_EDGE(2, s_px, s_py, s_qx, s_qy)
            CLIP_EDGE(3, s_qx, s_qy, s_px, s_py)

            float s = 0.0f;
            {
                float vx[8], vy[8];
                #pragma unroll
                for (int i = 0; i < 8; ++i) {
                    vx[i] = s_px[i * 64 + lane];
                    vy[i] = s_py[i * 64 + lane];
                }
                #pragma unroll
                for (int i = 0; i < 8; ++i) {
                    if (i < n) {
                        const bool wrap = (i + 1 == n);
                        const int  jn   = (i + 1) & 7;
                        const float qx = wrap ? vx[0] : vx[jn];
                        const float qy = wrap ? vy[0] : vy[jn];
                        s += vx[i] * qy - qx * vy[i];
                    }
                }
            }
            const float area = fabsf(0.5f * s);
            if (area > bestA || (area == bestA && p < bestI)) {
                bestA = area; bestI = p;
            }
        }
    }

    // 64-lane (area, min-idx) reduce — order-independent, deterministic
    #pragma unroll
    for (int off = 32; off; off >>= 1) {
        const float oa = __shfl_xor(bestA, off);
        const int   oi = __shfl_xor(bestI, off);
        if (oa > bestA || (oa == bestA && oi < bestI)) { bestA = oa; bestI = oi; }
    }

    const bool matched = (!gt_deg) && (bestA != 0.0f);
    const int label = labels[bg];

    if (matched) {
        const float* sc = scores + (size_t)(b * P_ + bestI) * C_;
        const float v0 = sc[lane];
        const bool  h2 = (lane + 64) < C_;
        const float v1 = h2 ? sc[lane + 64] : 0.0f;

        // packed (value, first-idx) key: mapped float in high 32, ~idx in
        // low 32 -> u64 max == (max value, min idx). Same selection as the
        // reference's first-occurrence argmax; unmap gives mx bit-exactly.
        unsigned long long key =
            ((unsigned long long)map_orderable(v0) << 32) |
            (unsigned)(0xFFFFFFFFu - (unsigned)lane);
        if (h2) {
            const unsigned long long key1 =
                ((unsigned long long)map_orderable(v1) << 32) |
                (unsigned)(0xFFFFFFFFu - (unsigned)(lane + 64));
            if (key1 > key) key = key1;
        }
        #pragma unroll
        for (int off = 32; off; off >>= 1) {
            const unsigned long long ok = __shfl_xor(key, off);
            if (ok > key) key = ok;
        }
        const unsigned mu = (unsigned)(key >> 32);
        const float mx = __uint_as_float((mu & 0x80000000u) ? (mu ^ 0x80000000u) : ~mu);
        const int   bi = (int)(0xFFFFFFFFu - (unsigned)(key & 0xFFFFFFFFu));

        float e = expf(v0 - mx) + (h2 ? expf(v1 - mx) : 0.0f);
        #pragma unroll
        for (int off = 32; off; off >>= 1) e += __shfl_xor(e, off);
        if (lane == 0) {
            ce_out[bg]   = mx + logf(e) - sc[label];
            corr_out[bg] = (bi == label) ? 1 : 0;
        }
    } else {
        if (lane == 0) {
            ce_out[bg]   = logf((float)C_);
            corr_out[bg] = 0;
        }
    }
}

// Finalize: single wave, float4/int4 loads, fixed order (deterministic).
__global__ __launch_bounds__(64) void finalize_kernel(
    const float* __restrict__ ce,
    const int*   __restrict__ corr,
    float* __restrict__ out)
{
    const int t = threadIdx.x;
    const float4* ce4 = (const float4*)ce;
    const int4*   co4 = (const int4*)corr;
    float a = 0.0f; int c = 0;
    #pragma unroll
    for (int r = 0; r < 4; ++r) {
        const float4 v = ce4[t + (r << 6)];
        a += (v.x + v.y) + (v.z + v.w);
        const int4 u = co4[t + (r << 6)];
        c += (u.x + u.y) + (u.z + u.w);
    }
    #pragma unroll
    for (int off = 32; off; off >>= 1) {
        a += __shfl_xor(a, off);
        c += __shfl_xor(c, off);
    }
    if (t == 0) {
        out[0] = a * (1.0f / (float)BG);  // mean ce
        out[1] = (float)BG;               // total_number
        out[2] = (float)c;                // rec_correct
    }
}

extern "C" void kernel_launch(void* const* d_in, const int* in_sizes, int n_in,
                              void* d_out, int out_size, void* d_ws, size_t ws_size,
                              hipStream_t stream) {
    const float* bboxes = (const float*)d_in[0];   // [B,P,9]
    const float* scores = (const float*)d_in[1];   // [B,P,C]
    const float* polys  = (const float*)d_in[2];   // [B,G,4,2]
    const int*   labels = (const int*)d_in[3];     // [B,G]
    float* out = (float*)d_out;

    float* ce = (float*)d_ws;                             // [BG]
    int*   cr = (int*)((char*)d_ws + BG * sizeof(float)); // [BG]

    match_kernel<<<BG, 256, 0, stream>>>(bboxes, scores, polys, labels, ce, cr);
    finalize_kernel<<<1, 64, 0, stream>>>(ce, cr, out);
}